// Round 1
// baseline (218.436 us; speedup 1.0000x reference)
//
#include <hip/hip_runtime.h>
#include <hip/hip_bf16.h>
#include <cmath>

#define D_MODEL 1024
#define SEQ     2048
#define BATCH   2
#define NH      16
#define HD      64
#define M_TOK   4096
#define THREE_D 3072

using bf16x8 = __bf16 __attribute__((ext_vector_type(8)));
using bf16x4 = __bf16 __attribute__((ext_vector_type(4)));
using f32x4  = float  __attribute__((ext_vector_type(4)));

// ---------------- cast fp32 -> bf16 (vectorized) ----------------
__global__ __launch_bounds__(256) void cast_kernel(const float* __restrict__ in,
                                                   __bf16* __restrict__ out, int n4) {
  int i = blockIdx.x * 256 + threadIdx.x;
  if (i < n4) {
    float4 f = reinterpret_cast<const float4*>(in)[i];
    bf16x4 o;
    o[0] = (__bf16)f.x; o[1] = (__bf16)f.y; o[2] = (__bf16)f.z; o[3] = (__bf16)f.w;
    reinterpret_cast<bf16x4*>(out)[i] = o;
  }
}

// ---------------- transpose + cast: in [R][C] f32 -> out [C][R] bf16 ----------------
__global__ __launch_bounds__(256) void transpose_cast(const float* __restrict__ in,
                                                      __bf16* __restrict__ out, int R, int C) {
  __shared__ float tile[64][65];
  int c0 = blockIdx.x * 64, r0 = blockIdx.y * 64;
  int tx = threadIdx.x & 63, ty = threadIdx.x >> 6;
#pragma unroll
  for (int i = 0; i < 16; ++i) {
    int r = ty + i * 4;
    tile[r][tx] = in[(size_t)(r0 + r) * C + c0 + tx];
  }
  __syncthreads();
#pragma unroll
  for (int i = 0; i < 16; ++i) {
    int r = ty + i * 4;  // row of out = column of in
    out[(size_t)(c0 + r) * R + r0 + tx] = (__bf16)tile[tx][r];
  }
}

// ---------------- bf16 MFMA GEMM: C[M][N] = A[M][K] * BT[N][K]^T + bias ----------------
// EPI 0: scatter to Q/K/V head-major bufs (scale Q by 0.125). EPI 1: fp32 out.
template <int EPI>
__global__ __launch_bounds__(256) void gemm_bt(const __bf16* __restrict__ A,
                                               const __bf16* __restrict__ BT,
                                               const float* __restrict__ bias,
                                               int Kdim, int Ncols,
                                               __bf16* __restrict__ qb, __bf16* __restrict__ kb,
                                               __bf16* __restrict__ vb, float* __restrict__ fout) {
  __shared__ __bf16 As[128][40];  // stride 40 (=32+8) kills bank conflicts, keeps 16B align
  __shared__ __bf16 Bs[128][40];
  const int tid  = threadIdx.x;
  const int lane = tid & 63, wave = tid >> 6;
  const int lr = lane & 15, lg = lane >> 4;
  const int wm = (wave >> 1) * 64, wn = (wave & 1) * 64;
  const int m0 = blockIdx.y * 128, n0 = blockIdx.x * 128;
  const int srow = tid >> 2, scol = (tid & 3) * 8;

  f32x4 acc[4][4];
  const f32x4 zero4 = {0.f, 0.f, 0.f, 0.f};
#pragma unroll
  for (int i = 0; i < 4; ++i)
#pragma unroll
    for (int j = 0; j < 4; ++j) acc[i][j] = zero4;

  const int ksteps = Kdim >> 5;
  for (int kk = 0; kk < ksteps; ++kk) {
    const int k0 = kk << 5;
    __syncthreads();
    {
      bf16x8 a0 = *reinterpret_cast<const bf16x8*>(A + (size_t)(m0 + srow) * Kdim + k0 + scol);
      bf16x8 a1 = *reinterpret_cast<const bf16x8*>(A + (size_t)(m0 + srow + 64) * Kdim + k0 + scol);
      bf16x8 b0 = *reinterpret_cast<const bf16x8*>(BT + (size_t)(n0 + srow) * Kdim + k0 + scol);
      bf16x8 b1 = *reinterpret_cast<const bf16x8*>(BT + (size_t)(n0 + srow + 64) * Kdim + k0 + scol);
      *reinterpret_cast<bf16x8*>(&As[srow][scol])      = a0;
      *reinterpret_cast<bf16x8*>(&As[srow + 64][scol]) = a1;
      *reinterpret_cast<bf16x8*>(&Bs[srow][scol])      = b0;
      *reinterpret_cast<bf16x8*>(&Bs[srow + 64][scol]) = b1;
    }
    __syncthreads();
    bf16x8 af[4], bfv[4];
#pragma unroll
    for (int i = 0; i < 4; ++i) af[i]  = *reinterpret_cast<const bf16x8*>(&As[wm + i * 16 + lr][lg * 8]);
#pragma unroll
    for (int j = 0; j < 4; ++j) bfv[j] = *reinterpret_cast<const bf16x8*>(&Bs[wn + j * 16 + lr][lg * 8]);
#pragma unroll
    for (int i = 0; i < 4; ++i)
#pragma unroll
      for (int j = 0; j < 4; ++j)
        acc[i][j] = __builtin_amdgcn_mfma_f32_16x16x32_bf16(af[i], bfv[j], acc[i][j], 0, 0, 0);
  }

#pragma unroll
  for (int i = 0; i < 4; ++i) {
#pragma unroll
    for (int j = 0; j < 4; ++j) {
      const int gc = n0 + wn + j * 16 + lr;
      const float bv = bias[gc];
#pragma unroll
      for (int ii = 0; ii < 4; ++ii) {
        const int gr = m0 + wm + i * 16 + lg * 4 + ii;
        float val = acc[i][j][ii] + bv;
        if (EPI == 0) {
          int t = gc >> 10, rem = gc & 1023;
          int h = rem >> 6, d = rem & 63;
          int b = gr >> 11, s = gr & 2047;
          size_t off = (((size_t)(b * NH + h)) * SEQ + s) * HD + d;
          if (t == 0)      qb[off] = (__bf16)(val * 0.125f);
          else if (t == 1) kb[off] = (__bf16)val;
          else             vb[off] = (__bf16)val;
        } else {
          fout[(size_t)gr * Ncols + gc] = val;
        }
      }
    }
  }
}

// ---------------- causal flash attention, head-major Q/K/V [BH][S][64] bf16 ----------------
__global__ __launch_bounds__(256) void attn_kernel(const __bf16* __restrict__ Q,
                                                   const __bf16* __restrict__ K,
                                                   const __bf16* __restrict__ V,
                                                   __bf16* __restrict__ AO) {
  __shared__ __bf16 Ks[64][72];
  __shared__ __bf16 Vt[64][72];      // transposed: Vt[d][key]
  __shared__ __bf16 Ps[4][32][72];   // per-wave P tile
  const int tid  = threadIdx.x;
  const int lane = tid & 63, wave = tid >> 6;
  const int lr = lane & 15, lg = lane >> 4;
  const int qt = blockIdx.x, bh = blockIdx.y;
  const int q0 = qt * 128;
  const size_t base = (size_t)bh * SEQ * HD;

  bf16x8 qf[2][2];
#pragma unroll
  for (int m = 0; m < 2; ++m)
#pragma unroll
    for (int kc = 0; kc < 2; ++kc)
      qf[m][kc] = *reinterpret_cast<const bf16x8*>(
          Q + base + (size_t)(q0 + wave * 32 + m * 16 + lr) * HD + kc * 32 + lg * 8);

  float mrun[2][4], lrun[2][4];
  f32x4 o[2][4];
  const f32x4 zero4 = {0.f, 0.f, 0.f, 0.f};
#pragma unroll
  for (int m = 0; m < 2; ++m) {
#pragma unroll
    for (int ii = 0; ii < 4; ++ii) { mrun[m][ii] = -__builtin_inff(); lrun[m][ii] = 0.f; }
#pragma unroll
    for (int nd = 0; nd < 4; ++nd) o[m][nd] = zero4;
  }

  const int nt = 2 * qt + 2;
  const int sr = tid >> 3, sc8 = (tid & 7) * 8;
  for (int t = 0; t < nt; ++t) {
    const int k0 = t * 64;
    __syncthreads();
#pragma unroll
    for (int p = 0; p < 2; ++p) {
      int row = sr + p * 32;
      bf16x8 kv = *reinterpret_cast<const bf16x8*>(K + base + (size_t)(k0 + row) * HD + sc8);
      *reinterpret_cast<bf16x8*>(&Ks[row][sc8]) = kv;
      bf16x8 vv = *reinterpret_cast<const bf16x8*>(V + base + (size_t)(k0 + row) * HD + sc8);
#pragma unroll
      for (int j = 0; j < 8; ++j) Vt[sc8 + j][row] = vv[j];
    }
    __syncthreads();
    const bool active = (q0 + wave * 32 + 31 >= k0);
    if (active) {
      f32x4 s[2][4];
#pragma unroll
      for (int m = 0; m < 2; ++m)
#pragma unroll
        for (int n = 0; n < 4; ++n) s[m][n] = zero4;
#pragma unroll
      for (int n = 0; n < 4; ++n) {
#pragma unroll
        for (int kc = 0; kc < 2; ++kc) {
          bf16x8 kf = *reinterpret_cast<const bf16x8*>(&Ks[n * 16 + lr][kc * 32 + lg * 8]);
#pragma unroll
          for (int m = 0; m < 2; ++m)
            s[m][n] = __builtin_amdgcn_mfma_f32_16x16x32_bf16(qf[m][kc], kf, s[m][n], 0, 0, 0);
        }
      }
      if (t >= 2 * qt) {  // diagonal tiles: causal mask
#pragma unroll
        for (int m = 0; m < 2; ++m)
#pragma unroll
          for (int n = 0; n < 4; ++n)
#pragma unroll
            for (int ii = 0; ii < 4; ++ii) {
              int qg = q0 + wave * 32 + m * 16 + lg * 4 + ii;
              int kg = k0 + n * 16 + lr;
              if (kg > qg) s[m][n][ii] = -__builtin_inff();
            }
      }
#pragma unroll
      for (int m = 0; m < 2; ++m) {
        float pm[4], mn[4], scl[4], ps[4];
#pragma unroll
        for (int ii = 0; ii < 4; ++ii)
          pm[ii] = fmaxf(fmaxf(s[m][0][ii], s[m][1][ii]), fmaxf(s[m][2][ii], s[m][3][ii]));
#pragma unroll
        for (int off = 1; off <= 8; off <<= 1)
#pragma unroll
          for (int ii = 0; ii < 4; ++ii) pm[ii] = fmaxf(pm[ii], __shfl_xor(pm[ii], off, 64));
#pragma unroll
        for (int ii = 0; ii < 4; ++ii) {
          mn[ii]  = fmaxf(mrun[m][ii], pm[ii]);
          scl[ii] = __expf(mrun[m][ii] - mn[ii]);
          ps[ii]  = 0.f;
        }
#pragma unroll
        for (int n = 0; n < 4; ++n)
#pragma unroll
          for (int ii = 0; ii < 4; ++ii) {
            float pv = __expf(s[m][n][ii] - mn[ii]);
            s[m][n][ii] = pv;
            ps[ii] += pv;
          }
#pragma unroll
        for (int off = 1; off <= 8; off <<= 1)
#pragma unroll
          for (int ii = 0; ii < 4; ++ii) ps[ii] += __shfl_xor(ps[ii], off, 64);
#pragma unroll
        for (int ii = 0; ii < 4; ++ii) {
          mrun[m][ii] = mn[ii];
          lrun[m][ii] = lrun[m][ii] * scl[ii] + ps[ii];
        }
#pragma unroll
        for (int nd = 0; nd < 4; ++nd)
#pragma unroll
          for (int ii = 0; ii < 4; ++ii) o[m][nd][ii] *= scl[ii];
#pragma unroll
        for (int n = 0; n < 4; ++n)
#pragma unroll
          for (int ii = 0; ii < 4; ++ii)
            Ps[wave][m * 16 + lg * 4 + ii][n * 16 + lr] = (__bf16)s[m][n][ii];
      }
    }
    __syncthreads();
    if (active) {
#pragma unroll
      for (int kc = 0; kc < 2; ++kc) {
        bf16x8 pa[2];
#pragma unroll
        for (int m = 0; m < 2; ++m)
          pa[m] = *reinterpret_cast<const bf16x8*>(&Ps[wave][m * 16 + lr][kc * 32 + lg * 8]);
#pragma unroll
        for (int nd = 0; nd < 4; ++nd) {
          bf16x8 vbf = *reinterpret_cast<const bf16x8*>(&Vt[nd * 16 + lr][kc * 32 + lg * 8]);
#pragma unroll
          for (int m = 0; m < 2; ++m)
            o[m][nd] = __builtin_amdgcn_mfma_f32_16x16x32_bf16(pa[m], vbf, o[m][nd], 0, 0, 0);
        }
      }
    }
  }

  const int b = bh >> 4, h = bh & 15;
#pragma unroll
  for (int m = 0; m < 2; ++m)
#pragma unroll
    for (int nd = 0; nd < 4; ++nd)
#pragma unroll
      for (int ii = 0; ii < 4; ++ii) {
        int row = q0 + wave * 32 + m * 16 + lg * 4 + ii;
        float val = o[m][nd][ii] / lrun[m][ii];
        AO[((size_t)(b * SEQ) + row) * D_MODEL + h * HD + nd * 16 + lr] = (__bf16)val;
      }
}

// ---------------- launch ----------------
extern "C" void kernel_launch(void* const* d_in, const int* in_sizes, int n_in,
                              void* d_out, int out_size, void* d_ws, size_t ws_size,
                              hipStream_t stream) {
  const float* x      = (const float*)d_in[0];
  const float* w_qkv  = (const float*)d_in[1];
  const float* b_qkv  = (const float*)d_in[2];
  const float* w_proj = (const float*)d_in[3];
  const float* b_proj = (const float*)d_in[4];
  float* out = (float*)d_out;

  char* ws = (char*)d_ws;
  __bf16* xb     = (__bf16*)(ws);                    // 4096*1024*2  = 8 MiB
  __bf16* wqkvT  = (__bf16*)(ws + 8388608);          // 3072*1024*2  = 6 MiB
  __bf16* wprojT = (__bf16*)(ws + 14680064);         // 1024*1024*2  = 2 MiB
  __bf16* qb     = (__bf16*)(ws + 16777216);         // 8 MiB
  __bf16* kb     = (__bf16*)(ws + 25165824);         // 8 MiB
  __bf16* vb     = (__bf16*)(ws + 33554432);         // 8 MiB
  __bf16* ao     = (__bf16*)(ws + 41943040);         // 8 MiB  (ends at 48 MiB)

  cast_kernel<<<4096, 256, 0, stream>>>(x, xb, M_TOK * D_MODEL / 4);
  transpose_cast<<<dim3(THREE_D / 64, D_MODEL / 64), 256, 0, stream>>>(w_qkv, wqkvT, D_MODEL, THREE_D);
  transpose_cast<<<dim3(D_MODEL / 64, D_MODEL / 64), 256, 0, stream>>>(w_proj, wprojT, D_MODEL, D_MODEL);

  gemm_bt<0><<<dim3(THREE_D / 128, M_TOK / 128), 256, 0, stream>>>(
      xb, wqkvT, b_qkv, D_MODEL, THREE_D, qb, kb, vb, nullptr);

  attn_kernel<<<dim3(SEQ / 128, BATCH * NH), 256, 0, stream>>>(qb, kb, vb, ao);

  gemm_bt<1><<<dim3(D_MODEL / 128, M_TOK / 128), 256, 0, stream>>>(
      ao, wprojT, b_proj, D_MODEL, D_MODEL, nullptr, nullptr, nullptr, out);
}

// Round 2
// 210.199 us; speedup vs baseline: 1.0392x; 1.0392x over previous
//
#include <hip/hip_runtime.h>
#include <hip/hip_bf16.h>
#include <cmath>

#define D_MODEL 1024
#define SEQ     2048
#define BATCH   2
#define NH      16
#define HD      64
#define M_TOK   4096
#define THREE_D 3072

using bf16x8 = __bf16 __attribute__((ext_vector_type(8)));
using bf16x4 = __bf16 __attribute__((ext_vector_type(4)));
using f32x4  = float  __attribute__((ext_vector_type(4)));

// ---------------- cast fp32 -> bf16 (vectorized) ----------------
__global__ __launch_bounds__(256) void cast_kernel(const float* __restrict__ in,
                                                   __bf16* __restrict__ out, int n4) {
  int i = blockIdx.x * 256 + threadIdx.x;
  if (i < n4) {
    float4 f = reinterpret_cast<const float4*>(in)[i];
    bf16x4 o;
    o[0] = (__bf16)f.x; o[1] = (__bf16)f.y; o[2] = (__bf16)f.z; o[3] = (__bf16)f.w;
    reinterpret_cast<bf16x4*>(out)[i] = o;
  }
}

// ---------------- transpose + cast: in [R][C] f32 -> out [C][R] bf16 ----------------
__global__ __launch_bounds__(256) void transpose_cast(const float* __restrict__ in,
                                                      __bf16* __restrict__ out, int R, int C) {
  __shared__ float tile[64][65];
  int c0 = blockIdx.x * 64, r0 = blockIdx.y * 64;
  int tx = threadIdx.x & 63, ty = threadIdx.x >> 6;
#pragma unroll
  for (int i = 0; i < 16; ++i) {
    int r = ty + i * 4;
    tile[r][tx] = in[(size_t)(r0 + r) * C + c0 + tx];
  }
  __syncthreads();
#pragma unroll
  for (int i = 0; i < 16; ++i) {
    int r = ty + i * 4;  // row of out = column of in
    out[(size_t)(c0 + r) * R + r0 + tx] = (__bf16)tile[tx][r];
  }
}

// ---------------- bf16 MFMA GEMM: C[M][N] = A[M][K] * BT[N][K]^T + bias ----------------
// EPI 0: scatter to Q/K/V bufs. Q scaled by 0.125, K row-major [bh][s][d],
//        V TRANSPOSED [bh][d][s] (for direct PV B-fragment loads in attn).
// EPI 1: fp32 out.
template <int EPI>
__global__ __launch_bounds__(256) void gemm_bt(const __bf16* __restrict__ A,
                                               const __bf16* __restrict__ BT,
                                               const float* __restrict__ bias,
                                               int Kdim, int Ncols,
                                               __bf16* __restrict__ qb, __bf16* __restrict__ kb,
                                               __bf16* __restrict__ vb, float* __restrict__ fout) {
  __shared__ __bf16 As[128][40];  // stride 40 keeps 16B align, avoids pow2 conflicts
  __shared__ __bf16 Bs[128][40];
  const int tid  = threadIdx.x;
  const int lane = tid & 63, wave = tid >> 6;
  const int lr = lane & 15, lg = lane >> 4;
  const int wm = (wave >> 1) * 64, wn = (wave & 1) * 64;
  const int m0 = blockIdx.y * 128, n0 = blockIdx.x * 128;
  const int srow = tid >> 2, scol = (tid & 3) * 8;

  f32x4 acc[4][4];
  const f32x4 zero4 = {0.f, 0.f, 0.f, 0.f};
#pragma unroll
  for (int i = 0; i < 4; ++i)
#pragma unroll
    for (int j = 0; j < 4; ++j) acc[i][j] = zero4;

  const int ksteps = Kdim >> 5;
  for (int kk = 0; kk < ksteps; ++kk) {
    const int k0 = kk << 5;
    __syncthreads();
    {
      bf16x8 a0 = *reinterpret_cast<const bf16x8*>(A + (size_t)(m0 + srow) * Kdim + k0 + scol);
      bf16x8 a1 = *reinterpret_cast<const bf16x8*>(A + (size_t)(m0 + srow + 64) * Kdim + k0 + scol);
      bf16x8 b0 = *reinterpret_cast<const bf16x8*>(BT + (size_t)(n0 + srow) * Kdim + k0 + scol);
      bf16x8 b1 = *reinterpret_cast<const bf16x8*>(BT + (size_t)(n0 + srow + 64) * Kdim + k0 + scol);
      *reinterpret_cast<bf16x8*>(&As[srow][scol])      = a0;
      *reinterpret_cast<bf16x8*>(&As[srow + 64][scol]) = a1;
      *reinterpret_cast<bf16x8*>(&Bs[srow][scol])      = b0;
      *reinterpret_cast<bf16x8*>(&Bs[srow + 64][scol]) = b1;
    }
    __syncthreads();
    bf16x8 af[4], bfv[4];
#pragma unroll
    for (int i = 0; i < 4; ++i) af[i]  = *reinterpret_cast<const bf16x8*>(&As[wm + i * 16 + lr][lg * 8]);
#pragma unroll
    for (int j = 0; j < 4; ++j) bfv[j] = *reinterpret_cast<const bf16x8*>(&Bs[wn + j * 16 + lr][lg * 8]);
#pragma unroll
    for (int i = 0; i < 4; ++i)
#pragma unroll
      for (int j = 0; j < 4; ++j)
        acc[i][j] = __builtin_amdgcn_mfma_f32_16x16x32_bf16(af[i], bfv[j], acc[i][j], 0, 0, 0);
  }

#pragma unroll
  for (int i = 0; i < 4; ++i) {
#pragma unroll
    for (int j = 0; j < 4; ++j) {
      const int gc = n0 + wn + j * 16 + lr;
      const float bv = bias[gc];
#pragma unroll
      for (int ii = 0; ii < 4; ++ii) {
        const int gr = m0 + wm + i * 16 + lg * 4 + ii;
        float val = acc[i][j][ii] + bv;
        if (EPI == 0) {
          int t = gc >> 10, rem = gc & 1023;
          int h = rem >> 6, d = rem & 63;
          int b = gr >> 11, s = gr & 2047;
          if (t == 0) {
            qb[(((size_t)(b * NH + h)) * SEQ + s) * HD + d] = (__bf16)(val * 0.125f);
          } else if (t == 1) {
            kb[(((size_t)(b * NH + h)) * SEQ + s) * HD + d] = (__bf16)val;
          } else {
            // transposed: [bh][d][s]
            vb[(((size_t)(b * NH + h)) * HD + d) * SEQ + s] = (__bf16)val;
          }
        } else {
          fout[(size_t)gr * Ncols + gc] = val;
        }
      }
    }
  }
}

// ---------------- causal flash attention, wave-per-block, no barriers ----------------
// Q,K: [bh][s][64] bf16 (Q pre-scaled). VT: [bh][64][s] bf16. One wave owns 32 q-rows.
__global__ __launch_bounds__(64) void attn_kernel(const __bf16* __restrict__ Q,
                                                  const __bf16* __restrict__ K,
                                                  const __bf16* __restrict__ VT,
                                                  __bf16* __restrict__ AO) {
  __shared__ __bf16 Ps[32][72];  // per-wave P tile (rows=q, cols=key), 4.6 KB
  const int lane = threadIdx.x;
  const int lr = lane & 15, lg = lane >> 4;

  // flat-id remap: c = XCD residue (groups 4 heads per residue class for L2 locality),
  // qt interleaves heavy/light tiles for causal load balance.
  const int f  = blockIdx.x;
  const int c  = f & 7;
  const int g  = f >> 3;
  const int bh = c + 8 * (g >> 6);
  const int qx = g & 63;
  const int qt = (qx & 1) ? (63 - (qx >> 1)) : (qx >> 1);

  const int q0 = qt * 32;
  const size_t base = (size_t)bh * SEQ * HD;  // same total size for K and VT

  bf16x8 qf[2][2];
#pragma unroll
  for (int m = 0; m < 2; ++m)
#pragma unroll
    for (int kc = 0; kc < 2; ++kc)
      qf[m][kc] = *reinterpret_cast<const bf16x8*>(
          Q + base + (size_t)(q0 + m * 16 + lr) * HD + kc * 32 + lg * 8);

  float mrun[2][4], lrun[2][4];
  f32x4 o[2][4];
  const f32x4 zero4 = {0.f, 0.f, 0.f, 0.f};
#pragma unroll
  for (int m = 0; m < 2; ++m) {
#pragma unroll
    for (int ii = 0; ii < 4; ++ii) { mrun[m][ii] = -__builtin_inff(); lrun[m][ii] = 0.f; }
#pragma unroll
    for (int nd = 0; nd < 4; ++nd) o[m][nd] = zero4;
  }

  const int nt = (qt >> 1) + 1;
  for (int t = 0; t < nt; ++t) {
    const int k0 = t * 64;
    const bool last = (t == nt - 1);
    // even-qt diagonal tile: upper 32 keys fully masked -> skip
    const int nmax = (last && !(qt & 1)) ? 2 : 4;
    const int kcmax = nmax >> 1;

    // ---- QK^T ----
    f32x4 s[2][4];
#pragma unroll
    for (int m = 0; m < 2; ++m)
#pragma unroll
      for (int n = 0; n < 4; ++n) s[m][n] = zero4;
#pragma unroll
    for (int kc = 0; kc < 2; ++kc) {
      bf16x8 kf[4];
#pragma unroll
      for (int n = 0; n < 4; ++n)
        if (n < nmax)
          kf[n] = *reinterpret_cast<const bf16x8*>(
              K + base + (size_t)(k0 + n * 16 + lr) * HD + kc * 32 + lg * 8);
#pragma unroll
      for (int n = 0; n < 4; ++n)
        if (n < nmax)
#pragma unroll
          for (int m = 0; m < 2; ++m)
            s[m][n] = __builtin_amdgcn_mfma_f32_16x16x32_bf16(qf[m][kc], kf[n], s[m][n], 0, 0, 0);
    }
    if (last) {  // causal mask on the diagonal tile
#pragma unroll
      for (int m = 0; m < 2; ++m)
#pragma unroll
        for (int n = 0; n < 4; ++n)
#pragma unroll
          for (int ii = 0; ii < 4; ++ii) {
            int qg = q0 + m * 16 + lg * 4 + ii;
            int kg = k0 + n * 16 + lr;
            if (kg > qg) s[m][n][ii] = -__builtin_inff();
          }
    }

    // ---- online softmax ----
#pragma unroll
    for (int m = 0; m < 2; ++m) {
      float pm[4], mn[4], scl[4], ps[4];
#pragma unroll
      for (int ii = 0; ii < 4; ++ii) {
        pm[ii] = fmaxf(s[m][0][ii], s[m][1][ii]);
        if (nmax == 4) pm[ii] = fmaxf(pm[ii], fmaxf(s[m][2][ii], s[m][3][ii]));
      }
#pragma unroll
      for (int off = 1; off <= 8; off <<= 1)
#pragma unroll
        for (int ii = 0; ii < 4; ++ii) pm[ii] = fmaxf(pm[ii], __shfl_xor(pm[ii], off, 64));
#pragma unroll
      for (int ii = 0; ii < 4; ++ii) {
        mn[ii]  = fmaxf(mrun[m][ii], pm[ii]);
        scl[ii] = __expf(mrun[m][ii] - mn[ii]);
        ps[ii]  = 0.f;
      }
#pragma unroll
      for (int n = 0; n < 4; ++n)
        if (n < nmax)
#pragma unroll
          for (int ii = 0; ii < 4; ++ii) {
            float pv = __expf(s[m][n][ii] - mn[ii]);
            s[m][n][ii] = pv;
            ps[ii] += pv;
          }
#pragma unroll
      for (int off = 1; off <= 8; off <<= 1)
#pragma unroll
        for (int ii = 0; ii < 4; ++ii) ps[ii] += __shfl_xor(ps[ii], off, 64);
#pragma unroll
      for (int ii = 0; ii < 4; ++ii) {
        mrun[m][ii] = mn[ii];
        lrun[m][ii] = lrun[m][ii] * scl[ii] + ps[ii];
      }
#pragma unroll
      for (int nd = 0; nd < 4; ++nd)
#pragma unroll
        for (int ii = 0; ii < 4; ++ii) o[m][nd][ii] *= scl[ii];
      // P -> per-wave LDS (re-fragmentation); same-wave, no barrier needed
#pragma unroll
      for (int n = 0; n < 4; ++n)
        if (n < nmax)
#pragma unroll
          for (int ii = 0; ii < 4; ++ii)
            Ps[m * 16 + lg * 4 + ii][n * 16 + lr] = (__bf16)s[m][n][ii];
    }

    // ---- PV ----
#pragma unroll
    for (int kc = 0; kc < 2; ++kc) {
      if (kc < kcmax) {
        bf16x8 pa[2];
#pragma unroll
        for (int m = 0; m < 2; ++m)
          pa[m] = *reinterpret_cast<const bf16x8*>(&Ps[m * 16 + lr][kc * 32 + lg * 8]);
#pragma unroll
        for (int nd = 0; nd < 4; ++nd) {
          bf16x8 vf = *reinterpret_cast<const bf16x8*>(
              VT + base + (size_t)(nd * 16 + lr) * SEQ + k0 + kc * 32 + lg * 8);
#pragma unroll
          for (int m = 0; m < 2; ++m)
            o[m][nd] = __builtin_amdgcn_mfma_f32_16x16x32_bf16(pa[m], vf, o[m][nd], 0, 0, 0);
        }
      }
    }
  }

  const int b = bh >> 4, h = bh & 15;
#pragma unroll
  for (int m = 0; m < 2; ++m)
#pragma unroll
    for (int nd = 0; nd < 4; ++nd)
#pragma unroll
      for (int ii = 0; ii < 4; ++ii) {
        int row = q0 + m * 16 + lg * 4 + ii;
        float val = o[m][nd][ii] / lrun[m][ii];
        AO[((size_t)(b * SEQ) + row) * D_MODEL + h * HD + nd * 16 + lr] = (__bf16)val;
      }
}

// ---------------- launch ----------------
extern "C" void kernel_launch(void* const* d_in, const int* in_sizes, int n_in,
                              void* d_out, int out_size, void* d_ws, size_t ws_size,
                              hipStream_t stream) {
  const float* x      = (const float*)d_in[0];
  const float* w_qkv  = (const float*)d_in[1];
  const float* b_qkv  = (const float*)d_in[2];
  const float* w_proj = (const float*)d_in[3];
  const float* b_proj = (const float*)d_in[4];
  float* out = (float*)d_out;

  char* ws = (char*)d_ws;
  __bf16* xb     = (__bf16*)(ws);                    // 4096*1024*2  = 8 MiB
  __bf16* wqkvT  = (__bf16*)(ws + 8388608);          // 3072*1024*2  = 6 MiB
  __bf16* wprojT = (__bf16*)(ws + 14680064);         // 1024*1024*2  = 2 MiB
  __bf16* qb     = (__bf16*)(ws + 16777216);         // 8 MiB
  __bf16* kb     = (__bf16*)(ws + 25165824);         // 8 MiB
  __bf16* vtb    = (__bf16*)(ws + 33554432);         // 8 MiB (transposed V)
  __bf16* ao     = (__bf16*)(ws + 41943040);         // 8 MiB  (ends at 48 MiB)

  cast_kernel<<<4096, 256, 0, stream>>>(x, xb, M_TOK * D_MODEL / 4);
  transpose_cast<<<dim3(THREE_D / 64, D_MODEL / 64), 256, 0, stream>>>(w_qkv, wqkvT, D_MODEL, THREE_D);
  transpose_cast<<<dim3(D_MODEL / 64, D_MODEL / 64), 256, 0, stream>>>(w_proj, wprojT, D_MODEL, D_MODEL);

  gemm_bt<0><<<dim3(THREE_D / 128, M_TOK / 128), 256, 0, stream>>>(
      xb, wqkvT, b_qkv, D_MODEL, THREE_D, qb, kb, vtb, nullptr);

  attn_kernel<<<2048, 64, 0, stream>>>(qb, kb, vtb, ao);

  gemm_bt<1><<<dim3(D_MODEL / 128, M_TOK / 128), 256, 0, stream>>>(
      ao, wprojT, b_proj, D_MODEL, D_MODEL, nullptr, nullptr, nullptr, out);
}

// Round 3
// 208.107 us; speedup vs baseline: 1.0496x; 1.0101x over previous
//
#include <hip/hip_runtime.h>
#include <hip/hip_bf16.h>

#define D_MODEL 1024
#define SEQ     2048
#define NH      16
#define HD      64
#define M_TOK   4096
#define THREE_D 3072

using bf16x8 = __bf16 __attribute__((ext_vector_type(8)));
using bf16x4 = __bf16 __attribute__((ext_vector_type(4)));
using f32x4  = float  __attribute__((ext_vector_type(4)));

typedef __attribute__((address_space(3))) uint32_t lds_u32;
typedef const __attribute__((address_space(1))) uint32_t glb_u32;

// ---------------- cast fp32 -> bf16 (vectorized) ----------------
__global__ __launch_bounds__(256) void cast_kernel(const float* __restrict__ in,
                                                   __bf16* __restrict__ out, int n4) {
  int i = blockIdx.x * 256 + threadIdx.x;
  if (i < n4) {
    float4 f = reinterpret_cast<const float4*>(in)[i];
    bf16x4 o;
    o[0] = (__bf16)f.x; o[1] = (__bf16)f.y; o[2] = (__bf16)f.z; o[3] = (__bf16)f.w;
    reinterpret_cast<bf16x4*>(out)[i] = o;
  }
}

// ---------------- transpose + cast: in [R][C] f32 -> out [C][R] bf16 ----------------
__global__ __launch_bounds__(256) void transpose_cast(const float* __restrict__ in,
                                                      __bf16* __restrict__ out, int R, int C) {
  __shared__ float tile[64][65];
  int c0 = blockIdx.x * 64, r0 = blockIdx.y * 64;
  int tx = threadIdx.x & 63, ty = threadIdx.x >> 6;
#pragma unroll
  for (int i = 0; i < 16; ++i) {
    int r = ty + i * 4;
    tile[r][tx] = in[(size_t)(r0 + r) * C + c0 + tx];
  }
  __syncthreads();
#pragma unroll
  for (int i = 0; i < 16; ++i) {
    int r = ty + i * 4;
    out[(size_t)(c0 + r) * R + r0 + tx] = (__bf16)tile[tx][r];
  }
}

// ---------------- bf16 MFMA GEMM (m97 structure): C = A * BT^T + bias ----------------
// Linear LDS [128][32] + global_load_lds width=16 staging.
// EPI 0: scatter to Q (scaled, [bh][s][d]) / K ([bh][s][d]) / V transposed ([bh][d][s]).
// EPI 1: fp32 out.
template <int EPI>
__global__ __launch_bounds__(256, 2) void gemm_bt(const __bf16* __restrict__ A,
                                                  const __bf16* __restrict__ BT,
                                                  const float* __restrict__ bias,
                                                  int Kdim, int Ncols,
                                                  __bf16* __restrict__ qb, __bf16* __restrict__ kb,
                                                  __bf16* __restrict__ vb, float* __restrict__ fout) {
  __shared__ __bf16 As[128 * 32];
  __shared__ __bf16 Bs[128 * 32];
  const int tid  = threadIdx.x;
  const int lane = tid & 63, wave = tid >> 6;
  const int lr = lane & 15, lg = lane >> 4;
  const int wm = (wave >> 1) * 64, wn = (wave & 1) * 64;
  const int m0 = blockIdx.y * 128, n0 = blockIdx.x * 128;
  const int srow = tid >> 2, scol = (tid & 3) * 8;

  f32x4 acc[4][4] = {};

  const __bf16* aSrc = A  + (size_t)(m0 + srow) * Kdim + scol;
  const __bf16* bSrc = BT + (size_t)(n0 + srow) * Kdim + scol;
  // wave-uniform LDS dest bases (HW writes base + lane*16)
  __bf16* aDst = As + wave * 512;
  __bf16* bDst = Bs + wave * 512;

  for (int k0 = 0; k0 < Kdim; k0 += 32) {
    __syncthreads();
    __builtin_amdgcn_global_load_lds((glb_u32*)(aSrc + k0),              (lds_u32*)aDst,          16, 0, 0);
    __builtin_amdgcn_global_load_lds((glb_u32*)(aSrc + 64 * Kdim + k0), (lds_u32*)(aDst + 2048), 16, 0, 0);
    __builtin_amdgcn_global_load_lds((glb_u32*)(bSrc + k0),              (lds_u32*)bDst,          16, 0, 0);
    __builtin_amdgcn_global_load_lds((glb_u32*)(bSrc + 64 * Kdim + k0), (lds_u32*)(bDst + 2048), 16, 0, 0);
    asm volatile("s_waitcnt vmcnt(0)" ::: "memory");
    __syncthreads();

    bf16x8 af[4], bfv[4];
#pragma unroll
    for (int i = 0; i < 4; ++i) af[i]  = *reinterpret_cast<const bf16x8*>(&As[(wm + i * 16 + lr) * 32 + lg * 8]);
#pragma unroll
    for (int j = 0; j < 4; ++j) bfv[j] = *reinterpret_cast<const bf16x8*>(&Bs[(wn + j * 16 + lr) * 32 + lg * 8]);
#pragma unroll
    for (int i = 0; i < 4; ++i)
#pragma unroll
      for (int j = 0; j < 4; ++j)
        acc[i][j] = __builtin_amdgcn_mfma_f32_16x16x32_bf16(af[i], bfv[j], acc[i][j], 0, 0, 0);
  }

#pragma unroll
  for (int i = 0; i < 4; ++i) {
#pragma unroll
    for (int j = 0; j < 4; ++j) {
      const int gc = n0 + wn + j * 16 + lr;
      const float bv = bias[gc];
#pragma unroll
      for (int ii = 0; ii < 4; ++ii) {
        const int gr = m0 + wm + i * 16 + lg * 4 + ii;
        float val = acc[i][j][ii] + bv;
        if (EPI == 0) {
          int t = gc >> 10, rem = gc & 1023;
          int h = rem >> 6, d = rem & 63;
          int b = gr >> 11, s = gr & 2047;
          if (t == 0) {
            qb[(((size_t)(b * NH + h)) * SEQ + s) * HD + d] = (__bf16)(val * 0.125f);
          } else if (t == 1) {
            kb[(((size_t)(b * NH + h)) * SEQ + s) * HD + d] = (__bf16)val;
          } else {
            vb[(((size_t)(b * NH + h)) * HD + d) * SEQ + s] = (__bf16)val;  // [bh][d][s]
          }
        } else {
          fout[(size_t)gr * Ncols + gc] = val;
        }
      }
    }
  }
}

// ---------------- causal flash attention: 1 wave = 16 q-rows, 4096 blocks ----------------
// Q,K: [bh][s][64] bf16 (Q pre-scaled). VT: [bh][64][s] bf16.
__global__ __launch_bounds__(64, 4) void attn_kernel(const __bf16* __restrict__ Q,
                                                     const __bf16* __restrict__ K,
                                                     const __bf16* __restrict__ VT,
                                                     __bf16* __restrict__ AO) {
  __shared__ __bf16 Ps[16][72];  // per-wave P tile, 2.3 KB
  const int lane = threadIdx.x;
  const int lr = lane & 15, lg = lane >> 4;

  // remap: XCD residue groups 4 heads; qt heavy-first for causal balance
  const int f  = blockIdx.x;
  const int c  = f & 7;
  const int u  = f >> 3;
  const int bh = c * 4 + (u & 3);
  const int qt = 127 - (u >> 2);

  const int q0 = qt * 16;
  const size_t base = (size_t)bh * SEQ * HD;

  bf16x8 qf[2];
#pragma unroll
  for (int kc = 0; kc < 2; ++kc)
    qf[kc] = *reinterpret_cast<const bf16x8*>(Q + base + (size_t)(q0 + lr) * HD + kc * 32 + lg * 8);

  float mrun[4], lrun[4];
  f32x4 o[4] = {};
#pragma unroll
  for (int ii = 0; ii < 4; ++ii) { mrun[ii] = -__builtin_inff(); lrun[ii] = 0.f; }

  const int nt = (qt >> 2) + 1;
  const int nmaxL = ((qt & 3) | 1) + 1;  // diagonal tile sub-tiles rounded to even (2 or 4)

  for (int t = 0; t < nt; ++t) {
    const int k0 = t * 64;
    const bool last = (t == nt - 1);
    const int nmax = last ? nmaxL : 4;
    const int kcmax = nmax >> 1;

    // ---- V prefetch (independent of QK; latency hides under MFMA+softmax) ----
    bf16x8 vf[2][4];
#pragma unroll
    for (int kc = 0; kc < 2; ++kc)
      if (kc < kcmax)
#pragma unroll
        for (int nd = 0; nd < 4; ++nd)
          vf[kc][nd] = *reinterpret_cast<const bf16x8*>(
              VT + base + (size_t)(nd * 16 + lr) * SEQ + k0 + kc * 32 + lg * 8);

    // ---- QK^T ----
    f32x4 s[4] = {};
#pragma unroll
    for (int kc = 0; kc < 2; ++kc) {
      bf16x8 kf[4];
#pragma unroll
      for (int n = 0; n < 4; ++n)
        if (n < nmax)
          kf[n] = *reinterpret_cast<const bf16x8*>(
              K + base + (size_t)(k0 + n * 16 + lr) * HD + kc * 32 + lg * 8);
#pragma unroll
      for (int n = 0; n < 4; ++n)
        if (n < nmax)
          s[n] = __builtin_amdgcn_mfma_f32_16x16x32_bf16(qf[kc], kf[n], s[n], 0, 0, 0);
    }
    if (last) {  // causal mask (also zeroes the padded even sub-tile via exp(-inf))
#pragma unroll
      for (int n = 0; n < 4; ++n)
        if (n < nmax)
#pragma unroll
          for (int ii = 0; ii < 4; ++ii) {
            int qg = q0 + lg * 4 + ii;
            int kg = k0 + n * 16 + lr;
            if (kg > qg) s[n][ii] = -__builtin_inff();
          }
    }

    // ---- online softmax (row = lr-group of 16 lanes) ----
    float pm[4], mn[4], scl[4], ps[4];
#pragma unroll
    for (int ii = 0; ii < 4; ++ii) {
      pm[ii] = fmaxf(s[0][ii], s[1][ii]);
      if (nmax == 4) pm[ii] = fmaxf(pm[ii], fmaxf(s[2][ii], s[3][ii]));
    }
#pragma unroll
    for (int off = 1; off <= 8; off <<= 1)
#pragma unroll
      for (int ii = 0; ii < 4; ++ii) pm[ii] = fmaxf(pm[ii], __shfl_xor(pm[ii], off, 64));
#pragma unroll
    for (int ii = 0; ii < 4; ++ii) {
      mn[ii]  = fmaxf(mrun[ii], pm[ii]);
      scl[ii] = __expf(mrun[ii] - mn[ii]);
      ps[ii]  = 0.f;
    }
#pragma unroll
    for (int n = 0; n < 4; ++n)
      if (n < nmax)
#pragma unroll
        for (int ii = 0; ii < 4; ++ii) {
          float pv = __expf(s[n][ii] - mn[ii]);
          s[n][ii] = pv;
          ps[ii] += pv;
        }
#pragma unroll
    for (int off = 1; off <= 8; off <<= 1)
#pragma unroll
      for (int ii = 0; ii < 4; ++ii) ps[ii] += __shfl_xor(ps[ii], off, 64);
#pragma unroll
    for (int ii = 0; ii < 4; ++ii) {
      mrun[ii] = mn[ii];
      lrun[ii] = lrun[ii] * scl[ii] + ps[ii];
    }
#pragma unroll
    for (int nd = 0; nd < 4; ++nd)
#pragma unroll
      for (int ii = 0; ii < 4; ++ii) o[nd][ii] *= scl[ii];

    // P -> per-wave LDS (same wave, no barrier)
#pragma unroll
    for (int n = 0; n < 4; ++n)
      if (n < nmax)
#pragma unroll
        for (int ii = 0; ii < 4; ++ii)
          Ps[lg * 4 + ii][n * 16 + lr] = (__bf16)s[n][ii];

    // ---- PV ----
#pragma unroll
    for (int kc = 0; kc < 2; ++kc) {
      if (kc < kcmax) {
        bf16x8 pa = *reinterpret_cast<const bf16x8*>(&Ps[lr][kc * 32 + lg * 8]);
#pragma unroll
        for (int nd = 0; nd < 4; ++nd)
          o[nd] = __builtin_amdgcn_mfma_f32_16x16x32_bf16(pa, vf[kc][nd], o[nd], 0, 0, 0);
      }
    }
  }

  const int b = bh >> 4, h = bh & 15;
  float rl[4];
#pragma unroll
  for (int ii = 0; ii < 4; ++ii) rl[ii] = 1.f / lrun[ii];
#pragma unroll
  for (int nd = 0; nd < 4; ++nd)
#pragma unroll
    for (int ii = 0; ii < 4; ++ii) {
      int row = q0 + lg * 4 + ii;
      AO[((size_t)(b * SEQ) + row) * D_MODEL + h * HD + nd * 16 + lr] = (__bf16)(o[nd][ii] * rl[ii]);
    }
}

// ---------------- launch ----------------
extern "C" void kernel_launch(void* const* d_in, const int* in_sizes, int n_in,
                              void* d_out, int out_size, void* d_ws, size_t ws_size,
                              hipStream_t stream) {
  const float* x      = (const float*)d_in[0];
  const float* w_qkv  = (const float*)d_in[1];
  const float* b_qkv  = (const float*)d_in[2];
  const float* w_proj = (const float*)d_in[3];
  const float* b_proj = (const float*)d_in[4];
  float* out = (float*)d_out;

  char* ws = (char*)d_ws;
  __bf16* xb     = (__bf16*)(ws);                    // 8 MiB
  __bf16* wqkvT  = (__bf16*)(ws + 8388608);          // 6 MiB
  __bf16* wprojT = (__bf16*)(ws + 14680064);         // 2 MiB
  __bf16* qb     = (__bf16*)(ws + 16777216);         // 8 MiB
  __bf16* kb     = (__bf16*)(ws + 25165824);         // 8 MiB
  __bf16* vtb    = (__bf16*)(ws + 33554432);         // 8 MiB (transposed V)
  __bf16* ao     = (__bf16*)(ws + 41943040);         // 8 MiB

  cast_kernel<<<4096, 256, 0, stream>>>(x, xb, M_TOK * D_MODEL / 4);
  transpose_cast<<<dim3(THREE_D / 64, D_MODEL / 64), 256, 0, stream>>>(w_qkv, wqkvT, D_MODEL, THREE_D);
  transpose_cast<<<dim3(D_MODEL / 64, D_MODEL / 64), 256, 0, stream>>>(w_proj, wprojT, D_MODEL, D_MODEL);

  gemm_bt<0><<<dim3(THREE_D / 128, M_TOK / 128), 256, 0, stream>>>(
      xb, wqkvT, b_qkv, D_MODEL, THREE_D, qb, kb, vtb, nullptr);

  attn_kernel<<<4096, 64, 0, stream>>>(qb, kb, vtb, ao);

  gemm_bt<1><<<dim3(D_MODEL / 128, M_TOK / 128), 256, 0, stream>>>(
      ao, wprojT, b_proj, D_MODEL, D_MODEL, nullptr, nullptr, nullptr, out);
}